// Round 1
// baseline (539.460 us; speedup 1.0000x reference)
//
#include <hip/hip_runtime.h>

// ---------------------------------------------------------------------------
// SymmetricCrossAttention, B=4, C=64, H=W=256, HEADS=1.
// Algebraic reduction: channel attention logits depend on the inputs only
// through G12 = X1 X2^T (64x64 per batch) and channel sums s1, s2.
// Outputs: out1 = M1 X2 + c1 + X1, out2 = M2 X1 + c2 + X2, with M,c tiny.
// Pipeline: k_zero -> k_gram (134MB read) -> k_mid (tiny) -> k_apply (RW).
// ---------------------------------------------------------------------------

#define NPIX 65536
#define SCALE 0.125f

// workspace float offsets
#define G_OFF   0        // 4 * 4096
#define S1_OFF  16384    // 4 * 64
#define S2_OFF  16640    // 4 * 64
#define MT_OFF  16896    // 2 sides * 4 batches * 4096 (M stored TRANSPOSED: Mt[j][o])
#define CV_OFF  49664    // 2 * 4 * 64
#define WS_FLOATS 50176

// ---- XOR-swizzled 64x64 fp32 LDS tile helpers (16B-block index ^ (row>>2)&7)
// Guarantees <=2-way bank aliasing (free) for row-contiguous float4 reads,
// column-strided float4 reads, and broadcast reads.
__device__ __forceinline__ int swzidx(int row, int k) {
  return (row << 6) + ((((k >> 2) ^ ((row >> 2) & 7)) << 2) | (k & 3));
}
__device__ __forceinline__ float ldswz1(const float* b, int row, int k) {
  return b[swzidx(row, k)];
}
__device__ __forceinline__ void stswz1(float* b, int row, int k, float v) {
  b[swzidx(row, k)] = v;
}
__device__ __forceinline__ float4 ldswz4f(const float* b, int row, int k) { // k % 4 == 0
  return *(const float4*)(b + (row << 6) + ((((k >> 2) ^ ((row >> 2) & 7)) << 2)));
}
__device__ __forceinline__ void stswz4f(float* b, int row, int k, float4 v) {
  *(float4*)(b + (row << 6) + ((((k >> 2) ^ ((row >> 2) & 7)) << 2))) = v;
}

// ---------------------------------------------------------------------------
__global__ void k_zero(float* __restrict__ ws) {
  int i = blockIdx.x * 256 + threadIdx.x;
  if (i < MT_OFF) ws[i] = 0.f;  // zero G, s1, s2
}

// ---------------------------------------------------------------------------
// Gram kernel: per batch, G12 = X1 X2^T (64x64) + channel sums.
// 512 blocks = 4 batches * 128 chunks; chunk = 512 px = 8 tiles of 64 px.
// Per block: 4 waves split-k (16 px each), 8x8 accumulator per lane.
__global__ __launch_bounds__(256) void k_gram(const float* __restrict__ x1,
                                              const float* __restrict__ x2,
                                              float* __restrict__ G,
                                              float* __restrict__ s1,
                                              float* __restrict__ s2) {
  __shared__ __align__(16) float A[4096];   // X1 tile [64ch][64px], swizzled
  __shared__ __align__(16) float Bt[4096];  // X2 tile
  const int tid = threadIdx.x;
  const int b = blockIdx.x >> 7;
  const int chunk = blockIdx.x & 127;
  const size_t base = ((size_t)b << 22) + ((size_t)chunk << 9);

  const int w = tid >> 6;          // wave 0..3 -> k-slice
  const int l = tid & 63;
  const int r0 = (l >> 3) << 3;    // 8 rows of G
  const int c0 = (l & 7) << 3;     // 8 cols of G

  float acc[8][8] = {{0.f}};
  float sum1[4] = {0.f, 0.f, 0.f, 0.f};
  float sum2[4] = {0.f, 0.f, 0.f, 0.f};

  for (int t = 0; t < 8; ++t) {
    __syncthreads();  // protect LDS from previous iteration's readers
#pragma unroll
    for (int r = 0; r < 4; ++r) {
      const int idx = (r << 8) + tid;
      const int c = idx >> 4;         // channel row
      const int p4 = idx & 15;        // pixel float4 block
      const size_t g = base + ((size_t)c << 16) + (t << 6) + (p4 << 2);
      const float4 v1 = *(const float4*)(x1 + g);
      const float4 v2 = *(const float4*)(x2 + g);
      stswz4f(A, c, p4 << 2, v1);
      stswz4f(Bt, c, p4 << 2, v2);
      sum1[r] += v1.x + v1.y + v1.z + v1.w;
      sum2[r] += v2.x + v2.y + v2.z + v2.w;
    }
    __syncthreads();
#pragma unroll
    for (int s = 0; s < 4; ++s) {
      const int kb = (w << 4) + (s << 2);
      float4 a[8], bb[8];
#pragma unroll
      for (int i = 0; i < 8; ++i) a[i] = ldswz4f(A, r0 + i, kb);
#pragma unroll
      for (int j = 0; j < 8; ++j) bb[j] = ldswz4f(Bt, c0 + j, kb);
#pragma unroll
      for (int i = 0; i < 8; ++i) {
#pragma unroll
        for (int j = 0; j < 8; ++j) {
          acc[i][j] += a[i].x * bb[j].x + a[i].y * bb[j].y +
                       a[i].z * bb[j].z + a[i].w * bb[j].w;
        }
      }
    }
  }

  float* Gb = G + (b << 12);
#pragma unroll
  for (int i = 0; i < 8; ++i) {
#pragma unroll
    for (int j = 0; j < 8; ++j) {
      atomicAdd(Gb + ((r0 + i) << 6) + c0 + j, acc[i][j]);
    }
  }
  // channel sums: 16 consecutive lanes share a channel -> shfl reduce
#pragma unroll
  for (int r = 0; r < 4; ++r) {
    const int c = ((r << 8) + tid) >> 4;
    float v1 = sum1[r], v2 = sum2[r];
#pragma unroll
    for (int d = 8; d >= 1; d >>= 1) {
      v1 += __shfl_down(v1, d, 16);
      v2 += __shfl_down(v2, d, 16);
    }
    if ((tid & 15) == 0) {
      atomicAdd(s1 + (b << 6) + c, v1);
      atomicAdd(s2 + (b << 6) + c, v2);
    }
  }
}

// ---------------------------------------------------------------------------
// 64x64 fp32 matmul in swizzled LDS. D[c][d] = sum_k A[c][k] * (TRANSB ? B[d][k] : B[k][d])
template <bool TRANSB>
__device__ __forceinline__ void mm64(const float* __restrict__ A, const float* __restrict__ B,
                                     float* __restrict__ D, int tid) {
  const int c0 = (tid >> 4) << 2;
  const int d0 = (tid & 15) << 2;
  float acc[4][4] = {{0.f}};
#pragma unroll
  for (int kb = 0; kb < 64; kb += 4) {
    float4 a[4];
#pragma unroll
    for (int i = 0; i < 4; ++i) a[i] = ldswz4f(A, c0 + i, kb);
    if (TRANSB) {
#pragma unroll
      for (int j = 0; j < 4; ++j) {
        const float4 bj = ldswz4f(B, d0 + j, kb);
#pragma unroll
        for (int i = 0; i < 4; ++i) {
          acc[i][j] += a[i].x * bj.x + a[i].y * bj.y + a[i].z * bj.z + a[i].w * bj.w;
        }
      }
    } else {
#pragma unroll
      for (int r = 0; r < 4; ++r) {
        const float4 q = ldswz4f(B, kb + r, d0);
        const float br[4] = {q.x, q.y, q.z, q.w};
#pragma unroll
        for (int i = 0; i < 4; ++i) {
          const float av = (r == 0) ? a[i].x : (r == 1) ? a[i].y : (r == 2) ? a[i].z : a[i].w;
#pragma unroll
          for (int j = 0; j < 4; ++j) acc[i][j] += av * br[j];
        }
      }
    }
  }
#pragma unroll
  for (int i = 0; i < 4; ++i) {
    stswz4f(D, c0 + i, d0, make_float4(acc[i][0], acc[i][1], acc[i][2], acc[i][3]));
  }
}

// M = A @ B (non-trans), stored TRANSPOSED to global: Mt[j][o] = M[o][j]
__device__ __forceinline__ void mm64_storeT(const float* __restrict__ A, const float* __restrict__ B,
                                            float* __restrict__ Mt, int tid) {
  const int c0 = (tid >> 4) << 2;
  const int d0 = (tid & 15) << 2;
  float acc[4][4] = {{0.f}};
#pragma unroll
  for (int kb = 0; kb < 64; kb += 4) {
    float4 a[4];
#pragma unroll
    for (int i = 0; i < 4; ++i) a[i] = ldswz4f(A, c0 + i, kb);
#pragma unroll
    for (int r = 0; r < 4; ++r) {
      const float4 q = ldswz4f(B, kb + r, d0);
      const float br[4] = {q.x, q.y, q.z, q.w};
#pragma unroll
      for (int i = 0; i < 4; ++i) {
        const float av = (r == 0) ? a[i].x : (r == 1) ? a[i].y : (r == 2) ? a[i].z : a[i].w;
#pragma unroll
        for (int j = 0; j < 4; ++j) acc[i][j] += av * br[j];
      }
    }
  }
#pragma unroll
  for (int i = 0; i < 4; ++i) {
#pragma unroll
    for (int j = 0; j < 4; ++j) {
      Mt[((d0 + j) << 6) + c0 + i] = acc[i][j];
    }
  }
}

__device__ __forceinline__ void load64x64(const float* __restrict__ g, float* __restrict__ lds, int tid) {
#pragma unroll
  for (int r = 0; r < 4; ++r) {
    const int idx = (r << 8) + tid;
    const int row = idx >> 4;
    const int b4 = (idx & 15) << 2;
    stswz4f(lds, row, b4, *(const float4*)(g + (row << 6) + b4));
  }
}

// ---------------------------------------------------------------------------
// Middle kernel: 8 blocks = 4 batches x 2 sides. Builds logits from G/s,
// softmax, then M (transposed) and c vectors into ws.
__global__ __launch_bounds__(256) void k_mid(
    const float* __restrict__ wq1, const float* __restrict__ bq1,
    const float* __restrict__ wk2, const float* __restrict__ bk2,
    const float* __restrict__ wv2, const float* __restrict__ bv2,
    const float* __restrict__ wo1, const float* __restrict__ bo1,
    const float* __restrict__ wq2, const float* __restrict__ bq2,
    const float* __restrict__ wk1, const float* __restrict__ bk1,
    const float* __restrict__ wv1, const float* __restrict__ bv1,
    const float* __restrict__ wo2, const float* __restrict__ bo2,
    float* __restrict__ ws) {
  __shared__ __align__(16) float LA[4096];
  __shared__ __align__(16) float LB[4096];
  __shared__ __align__(16) float LC[4096];
  __shared__ __align__(16) float LD[4096];
  __shared__ float vsq[64], vsk[64], vaq[64], vkk[64], vcv[64];

  const int tid = threadIdx.x;
  const int b = blockIdx.x >> 1;
  const int side = blockIdx.x & 1;

  const float *Wq, *Bq, *Wk, *Bk, *Wv, *Bv, *Wo, *Bo, *sqp, *skp;
  if (side == 0) {
    Wq = wq1; Bq = bq1; Wk = wk2; Bk = bk2; Wv = wv2; Bv = bv2; Wo = wo1; Bo = bo1;
    sqp = ws + S1_OFF + (b << 6); skp = ws + S2_OFF + (b << 6);
  } else {
    Wq = wq2; Bq = bq2; Wk = wk1; Bk = bk1; Wv = wv1; Bv = bv1; Wo = wo2; Bo = bo2;
    sqp = ws + S2_OFF + (b << 6); skp = ws + S1_OFF + (b << 6);
  }
  float* Mt = ws + MT_OFF + (((side << 2) + b) << 12);
  float* Cv = ws + CV_OFF + (((side << 2) + b) << 6);
  const float* G = ws + G_OFF + (b << 12);

  if (tid < 64) { vsq[tid] = sqp[tid]; vsk[tid] = skp[tid]; }
  load64x64(G, LA, tid);
  load64x64(Wq, LB, tid);
  __syncthreads();
  if (tid < 64) {  // aq = Wq @ sq
    float a = 0.f;
    for (int k = 0; k < 64; ++k) a += ldswz1(LB, tid, k) * vsq[k];
    vaq[tid] = a;
  }
  // T = Wq @ G (side0)  or  Wq @ G^T (side1)
  if (side == 0) mm64<false>(LB, LA, LC, tid);
  else           mm64<true >(LB, LA, LC, tid);
  __syncthreads();
  load64x64(Wk, LB, tid);
  __syncthreads();
  if (tid < 64) {  // kk = Wk @ sk
    float a = 0.f;
    for (int k = 0; k < 64; ++k) a += ldswz1(LB, tid, k) * vsk[k];
    vkk[tid] = a;
  }
  mm64<true>(LC, LB, LD, tid);  // S = T @ Wk^T
  __syncthreads();
  // assemble logits: S = scale*(S + aq[c]*bk[d] + bq[c]*(kk[d] + N*bk[d]))
#pragma unroll
  for (int t = 0; t < 16; ++t) {
    const int idx = (t << 8) + tid;
    const int c = idx >> 6, d = idx & 63;
    const float bkv = Bk[d], bqv = Bq[c];
    float v = ldswz1(LD, c, d);
    v = SCALE * (v + vaq[c] * bkv + bqv * (vkk[d] + 65536.f * bkv));
    stswz1(LD, c, d, v);
  }
  __syncthreads();
  {  // row softmax, 4 lanes per row
    const int row = tid >> 2, q = tid & 3;
    float ev[16];
    float mx = -3.4e38f;
#pragma unroll
    for (int t = 0; t < 16; ++t) { ev[t] = ldswz1(LD, row, q + (t << 2)); mx = fmaxf(mx, ev[t]); }
    mx = fmaxf(mx, __shfl_xor(mx, 1));
    mx = fmaxf(mx, __shfl_xor(mx, 2));
    float sm = 0.f;
#pragma unroll
    for (int t = 0; t < 16; ++t) { ev[t] = __expf(ev[t] - mx); sm += ev[t]; }
    sm += __shfl_xor(sm, 1);
    sm += __shfl_xor(sm, 2);
    const float inv = 1.f / sm;
#pragma unroll
    for (int t = 0; t < 16; ++t) stswz1(LD, row, q + (t << 2), ev[t] * inv);
  }
  __syncthreads();
  if (tid < 64) {  // cv = attn @ bv
    float a = 0.f;
    for (int d = 0; d < 64; ++d) a += ldswz1(LD, tid, d) * Bv[d];
    vcv[tid] = a;
  }
  load64x64(Wv, LB, tid);
  __syncthreads();
  mm64<false>(LD, LB, LC, tid);  // U = attn @ Wv
  __syncthreads();
  load64x64(Wo, LB, tid);
  __syncthreads();
  mm64_storeT(LB, LC, Mt, tid);  // Mt[j][o] = (Wo @ U)[o][j]
  if (tid < 64) {                // c = Wo @ cv + bo
    float a = 0.f;
    for (int c = 0; c < 64; ++c) a += ldswz1(LB, tid, c) * vcv[c];
    Cv[tid] = a + Bo[tid];
  }
}

// ---------------------------------------------------------------------------
// Apply kernel: one pixel per lane. out1 = M1 X2 + c1 + X1, out2 = M2 X1 + c2 + X2.
// Both 64-ch pixel vectors live in registers (static unroll); M rows are
// wave-uniform (scalar-cache) loads. No LDS.
__global__ __launch_bounds__(256) void k_apply(const float* __restrict__ x1,
                                               const float* __restrict__ x2,
                                               const float* __restrict__ ws,
                                               float* __restrict__ out) {
  const int b = blockIdx.x >> 8;
  const int p = ((blockIdx.x & 255) << 8) + threadIdx.x;
  const size_t fb = (size_t)b << 22;
  const float* X1 = x1 + fb;
  const float* X2 = x2 + fb;
  const float* Mt1 = ws + MT_OFF + ((size_t)b << 12);            // side 0
  const float* Mt2 = ws + MT_OFF + ((size_t)(4 + b) << 12);      // side 1
  const float* C1 = ws + CV_OFF + (b << 6);
  const float* C2 = ws + CV_OFF + ((4 + b) << 6);
  float* o1 = out + fb + p;
  float* o2 = out + ((size_t)1 << 24) + fb + p;

  float xr1[64], xr2[64];
#pragma unroll
  for (int j = 0; j < 64; ++j) {
    xr1[j] = X1[((size_t)j << 16) + p];
    xr2[j] = X2[((size_t)j << 16) + p];
  }

#pragma unroll 1
  for (int cc = 0; cc < 4; ++cc) {
    float a1[16], a2[16];
#pragma unroll
    for (int oi = 0; oi < 16; ++oi) {
      const int o = (cc << 4) + oi;
      a1[oi] = C1[o] + X1[((size_t)o << 16) + p];  // residual (cache hit)
      a2[oi] = C2[o] + X2[((size_t)o << 16) + p];
    }
#pragma unroll
    for (int j = 0; j < 64; ++j) {
      const float xx2 = xr2[j];
      const float xx1 = xr1[j];
      const float* m1 = Mt1 + (j << 6) + (cc << 4);
      const float* m2 = Mt2 + (j << 6) + (cc << 4);
#pragma unroll
      for (int oi = 0; oi < 16; ++oi) {
        a1[oi] += m1[oi] * xx2;
        a2[oi] += m2[oi] * xx1;
      }
    }
#pragma unroll
    for (int oi = 0; oi < 16; ++oi) {
      const int o = (cc << 4) + oi;
      o1[(size_t)o << 16] = a1[oi];
      o2[(size_t)o << 16] = a2[oi];
    }
  }
}

// ---------------------------------------------------------------------------
extern "C" void kernel_launch(void* const* d_in, const int* in_sizes, int n_in,
                              void* d_out, int out_size, void* d_ws, size_t ws_size,
                              hipStream_t stream) {
  const float* x1 = (const float*)d_in[0];
  const float* x2 = (const float*)d_in[1];
  float* ws = (float*)d_ws;
  float* out = (float*)d_out;

  k_zero<<<66, 256, 0, stream>>>(ws);
  k_gram<<<512, 256, 0, stream>>>(x1, x2, ws + G_OFF, ws + S1_OFF, ws + S2_OFF);
  k_mid<<<8, 256, 0, stream>>>(
      (const float*)d_in[2],  (const float*)d_in[3],   // w_q1, b_q1
      (const float*)d_in[4],  (const float*)d_in[5],   // w_k2, b_k2
      (const float*)d_in[6],  (const float*)d_in[7],   // w_v2, b_v2
      (const float*)d_in[14], (const float*)d_in[15],  // w_o1, b_o1
      (const float*)d_in[8],  (const float*)d_in[9],   // w_q2, b_q2
      (const float*)d_in[10], (const float*)d_in[11],  // w_k1, b_k1
      (const float*)d_in[12], (const float*)d_in[13],  // w_v1, b_v1
      (const float*)d_in[16], (const float*)d_in[17],  // w_o2, b_o2
      ws);
  k_apply<<<1024, 256, 0, stream>>>(x1, x2, ws, out);
}

// Round 2
// 255.479 us; speedup vs baseline: 2.1116x; 2.1116x over previous
//
#include <hip/hip_runtime.h>

// ---------------------------------------------------------------------------
// SymmetricCrossAttention, B=4, C=64, H=W=256, HEADS=1.
// Algebraic reduction: channel attention logits depend on the inputs only
// through G12 = X1 X2^T (64x64 per batch) and channel sums s1, s2.
// Outputs: out1 = M1 X2 + c1 + X1, out2 = M2 X1 + c2 + X2, with M,c tiny.
// Pipeline: k_gram (partials, no atomics) -> k_reduce -> k_mid -> k_apply.
// R2: removed all global atomics (they were HBM-side RMWs, 269MB write
// traffic, 390us). Blocks write private partials; k_reduce sums them.
// ---------------------------------------------------------------------------

#define NPIX 65536
#define SCALE 0.125f
#define NBLK_GRAM 512      // 4 batches * 128 chunks (512 px each)

// workspace float offsets
#define GP_OFF  0                      // 512 * 4096 partial Grams
#define SP_OFF  2097152                // 512 * 128 partial channel sums (s1|s2)
#define G_OFF   2162688                // 4 * 4096
#define S1_OFF  2179072                // 4 * 64
#define S2_OFF  2179328                // 4 * 64
#define MT_OFF  2179584                // 2*4*4096, M stored transposed Mt[j][o]
#define CV_OFF  2212352                // 2*4*64
#define WS_FLOATS 2212864              // ~8.85 MB

// ---- XOR-swizzled 64x64 fp32 LDS tile helpers (16B-block index ^ (row>>2)&7)
__device__ __forceinline__ int swzidx(int row, int k) {
  return (row << 6) + ((((k >> 2) ^ ((row >> 2) & 7)) << 2) | (k & 3));
}
__device__ __forceinline__ float ldswz1(const float* b, int row, int k) {
  return b[swzidx(row, k)];
}
__device__ __forceinline__ void stswz1(float* b, int row, int k, float v) {
  b[swzidx(row, k)] = v;
}
__device__ __forceinline__ float4 ldswz4f(const float* b, int row, int k) { // k%4==0
  return *(const float4*)(b + (row << 6) + ((((k >> 2) ^ ((row >> 2) & 7)) << 2)));
}
__device__ __forceinline__ void stswz4f(float* b, int row, int k, float4 v) {
  *(float4*)(b + (row << 6) + ((((k >> 2) ^ ((row >> 2) & 7)) << 2))) = v;
}

// ---- cross-wave accumulator exchange (rotated to spread banks)
__device__ __forceinline__ float* redptr(float* base, int l, int m) {
  return base + (l << 6) + (((m + l) & 15) << 2);
}
__device__ __forceinline__ void red_store(float* base, int l, const float acc[8][8]) {
#pragma unroll
  for (int m = 0; m < 16; ++m) {
    const int i = m >> 1, j0 = (m & 1) << 2;
    *(float4*)redptr(base, l, m) =
        make_float4(acc[i][j0], acc[i][j0 + 1], acc[i][j0 + 2], acc[i][j0 + 3]);
  }
}
__device__ __forceinline__ void red_add(const float* base, int l, float acc[8][8]) {
#pragma unroll
  for (int m = 0; m < 16; ++m) {
    const int i = m >> 1, j0 = (m & 1) << 2;
    const float4 v = *(const float4*)redptr(const_cast<float*>(base), l, m);
    acc[i][j0] += v.x; acc[i][j0 + 1] += v.y; acc[i][j0 + 2] += v.z; acc[i][j0 + 3] += v.w;
  }
}

// ---------------------------------------------------------------------------
// Gram kernel: per batch, G12 = X1 X2^T (64x64) + channel sums.
// 512 blocks = 4 batches * 128 chunks; chunk = 512 px = 8 tiles of 64 px.
// 4 waves split-k (16 px each), 8x8 accumulator per lane; cross-wave LDS
// reduce at end; wave 0 writes the block partial. NO atomics.
__global__ __launch_bounds__(256) void k_gram(const float* __restrict__ x1,
                                              const float* __restrict__ x2,
                                              float* __restrict__ gp,
                                              float* __restrict__ sp) {
  __shared__ __align__(16) float A[4096];   // X1 tile [64ch][64px], swizzled
  __shared__ __align__(16) float Bt[4096];  // X2 tile
  const int tid = threadIdx.x;
  const int b = blockIdx.x >> 7;
  const int chunk = blockIdx.x & 127;
  const size_t base = ((size_t)b << 22) + ((size_t)chunk << 9);

  const int w = tid >> 6;          // wave 0..3 -> k-slice
  const int l = tid & 63;
  const int r0 = (l >> 3) << 3;    // 8 rows of G
  const int c0 = (l & 7) << 3;     // 8 cols of G

  float acc[8][8] = {{0.f}};
  float sum1[4] = {0.f, 0.f, 0.f, 0.f};
  float sum2[4] = {0.f, 0.f, 0.f, 0.f};

  for (int t = 0; t < 8; ++t) {
    __syncthreads();  // protect LDS from previous iteration's readers
#pragma unroll
    for (int r = 0; r < 4; ++r) {
      const int idx = (r << 8) + tid;
      const int c = idx >> 4;         // channel row
      const int p4 = idx & 15;        // pixel float4 block
      const size_t g = base + ((size_t)c << 16) + (t << 6) + (p4 << 2);
      const float4 v1 = *(const float4*)(x1 + g);
      const float4 v2 = *(const float4*)(x2 + g);
      stswz4f(A, c, p4 << 2, v1);
      stswz4f(Bt, c, p4 << 2, v2);
      sum1[r] += v1.x + v1.y + v1.z + v1.w;
      sum2[r] += v2.x + v2.y + v2.z + v2.w;
    }
    __syncthreads();
#pragma unroll
    for (int s = 0; s < 4; ++s) {
      const int kb = (w << 4) + (s << 2);
      float4 a[8], bb[8];
#pragma unroll
      for (int i = 0; i < 8; ++i) a[i] = ldswz4f(A, r0 + i, kb);
#pragma unroll
      for (int j = 0; j < 8; ++j) bb[j] = ldswz4f(Bt, c0 + j, kb);
#pragma unroll
      for (int i = 0; i < 8; ++i) {
#pragma unroll
        for (int j = 0; j < 8; ++j) {
          acc[i][j] += a[i].x * bb[j].x + a[i].y * bb[j].y +
                       a[i].z * bb[j].z + a[i].w * bb[j].w;
        }
      }
    }
  }

  // channel sums -> per-block partial (16 consecutive lanes share a channel)
  float* spb = sp + (blockIdx.x << 7);
#pragma unroll
  for (int r = 0; r < 4; ++r) {
    const int c = ((r << 8) + tid) >> 4;
    float v1 = sum1[r], v2 = sum2[r];
#pragma unroll
    for (int d = 8; d >= 1; d >>= 1) {
      v1 += __shfl_down(v1, d, 16);
      v2 += __shfl_down(v2, d, 16);
    }
    if ((tid & 15) == 0) {
      spb[c] = v1;
      spb[64 + c] = v2;
    }
  }

  // cross-wave k-reduction (lane-aligned acc regions), reusing tile LDS
  __syncthreads();
  if (w == 1) red_store(A, l, acc);
  if (w == 3) red_store(Bt, l, acc);
  __syncthreads();
  if (w == 0) red_add(A, l, acc);
  if (w == 2) red_add(Bt, l, acc);
  __syncthreads();
  if (w == 2) red_store(A, l, acc);
  __syncthreads();
  if (w == 0) {
    red_add(A, l, acc);
    float* g = gp + ((size_t)blockIdx.x << 12);
#pragma unroll
    for (int i = 0; i < 8; ++i) {
      *(float4*)(g + ((r0 + i) << 6) + c0) =
          make_float4(acc[i][0], acc[i][1], acc[i][2], acc[i][3]);
      *(float4*)(g + ((r0 + i) << 6) + c0 + 4) =
          make_float4(acc[i][4], acc[i][5], acc[i][6], acc[i][7]);
    }
  }
}

// ---------------------------------------------------------------------------
// Reduce 128 partials per batch into final G and channel sums.
__global__ __launch_bounds__(256) void k_reduce(float* __restrict__ ws) {
  const int g = blockIdx.x;
  const int tid = threadIdx.x;
  if (g < 64) {
    const int idx = (g << 8) + tid;            // 0..16383
    const int b = idx >> 12, e = idx & 4095;
    const float* p = ws + GP_OFF + (((size_t)b << 7) << 12) + e;
    float a = 0.f;
#pragma unroll 8
    for (int k = 0; k < 128; ++k) a += p[(size_t)k << 12];
    ws[G_OFF + idx] = a;
  } else {
    const int b = g - 64;
    if (tid < 128) {
      const float* p = ws + SP_OFF + ((b << 7) << 7) + tid;
      float a = 0.f;
#pragma unroll 8
      for (int k = 0; k < 128; ++k) a += p[k << 7];
      if (tid < 64) ws[S1_OFF + (b << 6) + tid] = a;
      else          ws[S2_OFF + (b << 6) + (tid - 64)] = a;
    }
  }
}

// ---------------------------------------------------------------------------
// 64x64 fp32 matmul in swizzled LDS. D[c][d] = sum_k A[c][k] * (TRANSB ? B[d][k] : B[k][d])
template <bool TRANSB>
__device__ __forceinline__ void mm64(const float* __restrict__ A, const float* __restrict__ B,
                                     float* __restrict__ D, int tid) {
  const int c0 = (tid >> 4) << 2;
  const int d0 = (tid & 15) << 2;
  float acc[4][4] = {{0.f}};
#pragma unroll
  for (int kb = 0; kb < 64; kb += 4) {
    float4 a[4];
#pragma unroll
    for (int i = 0; i < 4; ++i) a[i] = ldswz4f(A, c0 + i, kb);
    if (TRANSB) {
#pragma unroll
      for (int j = 0; j < 4; ++j) {
        const float4 bj = ldswz4f(B, d0 + j, kb);
#pragma unroll
        for (int i = 0; i < 4; ++i) {
          acc[i][j] += a[i].x * bj.x + a[i].y * bj.y + a[i].z * bj.z + a[i].w * bj.w;
        }
      }
    } else {
#pragma unroll
      for (int r = 0; r < 4; ++r) {
        const float4 q = ldswz4f(B, kb + r, d0);
        const float br[4] = {q.x, q.y, q.z, q.w};
#pragma unroll
        for (int i = 0; i < 4; ++i) {
          const float av = (r == 0) ? a[i].x : (r == 1) ? a[i].y : (r == 2) ? a[i].z : a[i].w;
#pragma unroll
          for (int j = 0; j < 4; ++j) acc[i][j] += av * br[j];
        }
      }
    }
  }
#pragma unroll
  for (int i = 0; i < 4; ++i) {
    stswz4f(D, c0 + i, d0, make_float4(acc[i][0], acc[i][1], acc[i][2], acc[i][3]));
  }
}

// M = A @ B (non-trans), stored TRANSPOSED to global: Mt[j][o] = M[o][j]
__device__ __forceinline__ void mm64_storeT(const float* __restrict__ A, const float* __restrict__ B,
                                            float* __restrict__ Mt, int tid) {
  const int c0 = (tid >> 4) << 2;
  const int d0 = (tid & 15) << 2;
  float acc[4][4] = {{0.f}};
#pragma unroll
  for (int kb = 0; kb < 64; kb += 4) {
    float4 a[4];
#pragma unroll
    for (int i = 0; i < 4; ++i) a[i] = ldswz4f(A, c0 + i, kb);
#pragma unroll
    for (int r = 0; r < 4; ++r) {
      const float4 q = ldswz4f(B, kb + r, d0);
      const float br[4] = {q.x, q.y, q.z, q.w};
#pragma unroll
      for (int i = 0; i < 4; ++i) {
        const float av = (r == 0) ? a[i].x : (r == 1) ? a[i].y : (r == 2) ? a[i].z : a[i].w;
#pragma unroll
        for (int j = 0; j < 4; ++j) acc[i][j] += av * br[j];
      }
    }
  }
#pragma unroll
  for (int i = 0; i < 4; ++i) {
#pragma unroll
    for (int j = 0; j < 4; ++j) {
      Mt[((d0 + j) << 6) + c0 + i] = acc[i][j];
    }
  }
}

__device__ __forceinline__ void load64x64(const float* __restrict__ g, float* __restrict__ lds, int tid) {
#pragma unroll
  for (int r = 0; r < 4; ++r) {
    const int idx = (r << 8) + tid;
    const int row = idx >> 4;
    const int b4 = (idx & 15) << 2;
    stswz4f(lds, row, b4, *(const float4*)(g + (row << 6) + b4));
  }
}

// ---------------------------------------------------------------------------
// Middle kernel: 8 blocks = 4 batches x 2 sides. Builds logits from G/s,
// softmax, then M (transposed) and c vectors into ws.
__global__ __launch_bounds__(256) void k_mid(
    const float* __restrict__ wq1, const float* __restrict__ bq1,
    const float* __restrict__ wk2, const float* __restrict__ bk2,
    const float* __restrict__ wv2, const float* __restrict__ bv2,
    const float* __restrict__ wo1, const float* __restrict__ bo1,
    const float* __restrict__ wq2, const float* __restrict__ bq2,
    const float* __restrict__ wk1, const float* __restrict__ bk1,
    const float* __restrict__ wv1, const float* __restrict__ bv1,
    const float* __restrict__ wo2, const float* __restrict__ bo2,
    float* __restrict__ ws) {
  __shared__ __align__(16) float LA[4096];
  __shared__ __align__(16) float LB[4096];
  __shared__ __align__(16) float LC[4096];
  __shared__ __align__(16) float LD[4096];
  __shared__ float vsq[64], vsk[64], vaq[64], vkk[64], vcv[64];

  const int tid = threadIdx.x;
  const int b = blockIdx.x >> 1;
  const int side = blockIdx.x & 1;

  const float *Wq, *Bq, *Wk, *Bk, *Wv, *Bv, *Wo, *Bo, *sqp, *skp;
  if (side == 0) {
    Wq = wq1; Bq = bq1; Wk = wk2; Bk = bk2; Wv = wv2; Bv = bv2; Wo = wo1; Bo = bo1;
    sqp = ws + S1_OFF + (b << 6); skp = ws + S2_OFF + (b << 6);
  } else {
    Wq = wq2; Bq = bq2; Wk = wk1; Bk = bk1; Wv = wv1; Bv = bv1; Wo = wo2; Bo = bo2;
    sqp = ws + S2_OFF + (b << 6); skp = ws + S1_OFF + (b << 6);
  }
  float* Mt = ws + MT_OFF + (((side << 2) + b) << 12);
  float* Cv = ws + CV_OFF + (((side << 2) + b) << 6);
  const float* G = ws + G_OFF + (b << 12);

  if (tid < 64) { vsq[tid] = sqp[tid]; vsk[tid] = skp[tid]; }
  load64x64(G, LA, tid);
  load64x64(Wq, LB, tid);
  __syncthreads();
  if (tid < 64) {  // aq = Wq @ sq
    float a = 0.f;
    for (int k = 0; k < 64; ++k) a += ldswz1(LB, tid, k) * vsq[k];
    vaq[tid] = a;
  }
  // T = Wq @ G (side0)  or  Wq @ G^T (side1)
  if (side == 0) mm64<false>(LB, LA, LC, tid);
  else           mm64<true >(LB, LA, LC, tid);
  __syncthreads();
  load64x64(Wk, LB, tid);
  __syncthreads();
  if (tid < 64) {  // kk = Wk @ sk
    float a = 0.f;
    for (int k = 0; k < 64; ++k) a += ldswz1(LB, tid, k) * vsk[k];
    vkk[tid] = a;
  }
  mm64<true>(LC, LB, LD, tid);  // S = T @ Wk^T
  __syncthreads();
  // assemble logits: S = scale*(S + aq[c]*bk[d] + bq[c]*(kk[d] + N*bk[d]))
#pragma unroll
  for (int t = 0; t < 16; ++t) {
    const int idx = (t << 8) + tid;
    const int c = idx >> 6, d = idx & 63;
    const float bkv = Bk[d], bqv = Bq[c];
    float v = ldswz1(LD, c, d);
    v = SCALE * (v + vaq[c] * bkv + bqv * (vkk[d] + 65536.f * bkv));
    stswz1(LD, c, d, v);
  }
  __syncthreads();
  {  // row softmax, 4 lanes per row
    const int row = tid >> 2, q = tid & 3;
    float ev[16];
    float mx = -3.4e38f;
#pragma unroll
    for (int t = 0; t < 16; ++t) { ev[t] = ldswz1(LD, row, q + (t << 2)); mx = fmaxf(mx, ev[t]); }
    mx = fmaxf(mx, __shfl_xor(mx, 1));
    mx = fmaxf(mx, __shfl_xor(mx, 2));
    float sm = 0.f;
#pragma unroll
    for (int t = 0; t < 16; ++t) { ev[t] = __expf(ev[t] - mx); sm += ev[t]; }
    sm += __shfl_xor(sm, 1);
    sm += __shfl_xor(sm, 2);
    const float inv = 1.f / sm;
#pragma unroll
    for (int t = 0; t < 16; ++t) stswz1(LD, row, q + (t << 2), ev[t] * inv);
  }
  __syncthreads();
  if (tid < 64) {  // cv = attn @ bv
    float a = 0.f;
    for (int d = 0; d < 64; ++d) a += ldswz1(LD, tid, d) * Bv[d];
    vcv[tid] = a;
  }
  load64x64(Wv, LB, tid);
  __syncthreads();
  mm64<false>(LD, LB, LC, tid);  // U = attn @ Wv
  __syncthreads();
  load64x64(Wo, LB, tid);
  __syncthreads();
  mm64_storeT(LB, LC, Mt, tid);  // Mt[j][o] = (Wo @ U)[o][j]
  if (tid < 64) {                // c = Wo @ cv + bo
    float a = 0.f;
    for (int c = 0; c < 64; ++c) a += ldswz1(LB, tid, c) * vcv[c];
    Cv[tid] = a + Bo[tid];
  }
}

// ---------------------------------------------------------------------------
// Apply kernel: one pixel per lane. out1 = M1 X2 + c1 + X1, out2 = M2 X1 + c2 + X2.
// Both 64-ch pixel vectors live in registers (static unroll); M rows are
// wave-uniform (scalar-cache) loads. No LDS.
__global__ __launch_bounds__(256) void k_apply(const float* __restrict__ x1,
                                               const float* __restrict__ x2,
                                               const float* __restrict__ ws,
                                               float* __restrict__ out) {
  const int b = blockIdx.x >> 8;
  const int p = ((blockIdx.x & 255) << 8) + threadIdx.x;
  const size_t fb = (size_t)b << 22;
  const float* X1 = x1 + fb;
  const float* X2 = x2 + fb;
  const float* Mt1 = ws + MT_OFF + ((size_t)b << 12);            // side 0
  const float* Mt2 = ws + MT_OFF + ((size_t)(4 + b) << 12);      // side 1
  const float* C1 = ws + CV_OFF + (b << 6);
  const float* C2 = ws + CV_OFF + ((4 + b) << 6);
  float* o1 = out + fb + p;
  float* o2 = out + ((size_t)1 << 24) + fb + p;

  float xr1[64], xr2[64];
#pragma unroll
  for (int j = 0; j < 64; ++j) {
    xr1[j] = X1[((size_t)j << 16) + p];
    xr2[j] = X2[((size_t)j << 16) + p];
  }

#pragma unroll 1
  for (int cc = 0; cc < 4; ++cc) {
    float a1[16], a2[16];
#pragma unroll
    for (int oi = 0; oi < 16; ++oi) {
      const int o = (cc << 4) + oi;
      a1[oi] = C1[o] + X1[((size_t)o << 16) + p];  // residual (cache hit)
      a2[oi] = C2[o] + X2[((size_t)o << 16) + p];
    }
#pragma unroll
    for (int j = 0; j < 64; ++j) {
      const float xx2 = xr2[j];
      const float xx1 = xr1[j];
      const float* m1 = Mt1 + (j << 6) + (cc << 4);
      const float* m2 = Mt2 + (j << 6) + (cc << 4);
#pragma unroll
      for (int oi = 0; oi < 16; ++oi) {
        a1[oi] += m1[oi] * xx2;
        a2[oi] += m2[oi] * xx1;
      }
    }
#pragma unroll
    for (int oi = 0; oi < 16; ++oi) {
      const int o = (cc << 4) + oi;
      o1[(size_t)o << 16] = a1[oi];
      o2[(size_t)o << 16] = a2[oi];
    }
  }
}

// ---------------------------------------------------------------------------
extern "C" void kernel_launch(void* const* d_in, const int* in_sizes, int n_in,
                              void* d_out, int out_size, void* d_ws, size_t ws_size,
                              hipStream_t stream) {
  const float* x1 = (const float*)d_in[0];
  const float* x2 = (const float*)d_in[1];
  float* ws = (float*)d_ws;
  float* out = (float*)d_out;

  k_gram<<<NBLK_GRAM, 256, 0, stream>>>(x1, x2, ws + GP_OFF, ws + SP_OFF);
  k_reduce<<<68, 256, 0, stream>>>(ws);
  k_mid<<<8, 256, 0, stream>>>(
      (const float*)d_in[2],  (const float*)d_in[3],   // w_q1, b_q1
      (const float*)d_in[4],  (const float*)d_in[5],   // w_k2, b_k2
      (const float*)d_in[6],  (const float*)d_in[7],   // w_v2, b_v2
      (const float*)d_in[14], (const float*)d_in[15],  // w_o1, b_o1
      (const float*)d_in[8],  (const float*)d_in[9],   // w_q2, b_q2
      (const float*)d_in[10], (const float*)d_in[11],  // w_k1, b_k1
      (const float*)d_in[12], (const float*)d_in[13],  // w_v1, b_v1
      (const float*)d_in[16], (const float*)d_in[17],  // w_o2, b_o2
      ws);
  k_apply<<<1024, 256, 0, stream>>>(x1, x2, ws, out);
}